// Round 2
// baseline (651.077 us; speedup 1.0000x reference)
//
#include <hip/hip_runtime.h>
#include <math.h>

#define NN 846
#define KK 64
#define DD 256
constexpr float BN_EPS = 1e-5f;

__device__ __forceinline__ float wave_reduce_sum(float v) {
#pragma unroll
  for (int m = 32; m > 0; m >>= 1) v += __shfl_xor(v, m, 64);
  return v;
}

extern "C" __global__ __launch_bounds__(256, 4) void fused_gnn(
    const int* __restrict__ drug_name,
    const int* __restrict__ adj_tail,
    const int* __restrict__ adj_rel,
    const float* __restrict__ drug_table,
    const float* __restrict__ rela_table,
    const float* __restrict__ ent_table,
    const float* __restrict__ W1,
    const float* __restrict__ b1,
    const float* __restrict__ W2,
    const float* __restrict__ b2,
    const float* __restrict__ lin_w,
    const float* __restrict__ lin_b,
    float* __restrict__ x_out) {
  // DR chunk, TRANSPOSED: [dd][k]. Row stride 68 floats = 272 B (16B-aligned,
  // bank phase +4 per row -> scalar column writes are 2-way = free; GEMM reads
  // are same-address broadcasts).
  __shared__ float s_dr_t[64][68];
  __shared__ float s_w2s[256];      // row-sums of W2[n]
  __shared__ float s_b2p[64][5];    // b2 row-sum partials (4 segs + pad)
  __shared__ float s_drug[256];
  __shared__ float s_de[512];       // concat(weighted, drug)
  __shared__ float s_score[64];
  __shared__ float s_logits[64];
  __shared__ int s_rel[64];
  __shared__ int s_tail[64];

  const int n = blockIdx.x;
  const int tid = threadIdx.x;
  const int wv = tid >> 6;   // wave 0..3
  const int kr = tid >> 5;   // 0..7  (k-tile row)
  const int ec = tid & 31;   // 0..31 (e-tile col)
  const int e0 = ec * 8;
  const int k0 = kr * 8;

  if (tid < 64) {
    s_rel[tid] = adj_rel[n * KK + tid];
    s_tail[tid] = adj_tail[n * KK + tid];
  }
  const int dn = drug_name[n];
  s_drug[tid] = drug_table[(size_t)dn * DD + tid];

  // ---- b2 row-sum partials: 4 threads per row, 64B segments (L2-resident) ----
  {
    const int row = tid >> 2, seg = tid & 3;
    const float4* p = (const float4*)(b2 + (size_t)row * DD + seg * 64);
    float4 s4 = make_float4(0.f, 0.f, 0.f, 0.f);
#pragma unroll
    for (int j = 0; j < 16; ++j) {
      const float4 v = p[j];
      s4.x += v.x; s4.y += v.y; s4.z += v.z; s4.w += v.w;
    }
    s_b2p[row][seg] = s4.x + s4.y + s4.z + s4.w;
  }

  const float* W1n = W1 + (size_t)n * DD * DD;
  const float* W2n = W2 + (size_t)n * DD * DD;

  float acc[8][8];
#pragma unroll
  for (int i = 0; i < 8; ++i)
#pragma unroll
    for (int j = 0; j < 8; ++j) acc[i][j] = 0.f;

  float w2acc = 0.f;  // thread owns W2 row `tid`, accumulated across chunks

  for (int c = 0; c < 4; ++c) {
    const int d0 = c * 64;
    __syncthreads();  // prev-chunk readers of s_dr_t done (also initial visibility)

    // ---- build DR_T chunk: s_dr_t[dd][k] = drug[d0+dd] * rela[rel[k]][d0+dd] ----
    {
      const int kq = tid & 63;
      const int dq = wv * 16;
      const float* rr = rela_table + (size_t)s_rel[kq] * DD + d0 + dq;
      const float4 r0 = *(const float4*)(rr + 0);
      const float4 r1 = *(const float4*)(rr + 4);
      const float4 r2 = *(const float4*)(rr + 8);
      const float4 r3 = *(const float4*)(rr + 12);
      const float rv[16] = {r0.x, r0.y, r0.z, r0.w, r1.x, r1.y, r1.z, r1.w,
                            r2.x, r2.y, r2.z, r2.w, r3.x, r3.y, r3.z, r3.w};
#pragma unroll
      for (int u = 0; u < 16; ++u)
        s_dr_t[dq + u][kq] = s_drug[d0 + dq + u] * rv[u];
    }

    // ---- W2 row-sum slice for this chunk: own row, 16 float4, pure ILP ----
    {
      const float4* p = (const float4*)(W2n + (size_t)tid * DD + d0);
      float4 s4 = make_float4(0.f, 0.f, 0.f, 0.f);
#pragma unroll
      for (int j = 0; j < 16; ++j) {
        const float4 v = p[j];
        s4.x += v.x; s4.y += v.y; s4.z += v.z; s4.w += v.w;
      }
      w2acc += s4.x + s4.y + s4.z + s4.w;
    }

    __syncthreads();  // DR_T ready

    // ---- barrier-free GEMM over this chunk: W1 direct global->reg ----
    const float* wbase = W1n + (size_t)d0 * DD + e0;
#pragma unroll 2
    for (int dd = 0; dd < 64; ++dd) {
      const float4 a0 = *(const float4*)&s_dr_t[dd][k0];
      const float4 a1 = *(const float4*)&s_dr_t[dd][k0 + 4];
      const float4 w0 = *(const float4*)(wbase + (size_t)dd * DD);
      const float4 w1v = *(const float4*)(wbase + (size_t)dd * DD + 4);
      const float av[8] = {a0.x, a0.y, a0.z, a0.w, a1.x, a1.y, a1.z, a1.w};
#pragma unroll
      for (int i = 0; i < 8; ++i) {
        acc[i][0] = fmaf(av[i], w0.x, acc[i][0]);
        acc[i][1] = fmaf(av[i], w0.y, acc[i][1]);
        acc[i][2] = fmaf(av[i], w0.z, acc[i][2]);
        acc[i][3] = fmaf(av[i], w0.w, acc[i][3]);
        acc[i][4] = fmaf(av[i], w1v.x, acc[i][4]);
        acc[i][5] = fmaf(av[i], w1v.y, acc[i][5]);
        acc[i][6] = fmaf(av[i], w1v.z, acc[i][6]);
        acc[i][7] = fmaf(av[i], w1v.w, acc[i][7]);
      }
    }
  }

  s_w2s[tid] = w2acc;
  __syncthreads();

  // ---- epilogue: h1 = relu(acc + b1); logit[k] = dot(h1[k,:], W2s) + b2s[k] ----
  const float4 wa = *(const float4*)&s_w2s[e0];
  const float4 wb = *(const float4*)&s_w2s[e0 + 4];
  float lg[8];
#pragma unroll
  for (int i = 0; i < 8; ++i) {
    const float* b1r = b1 + (size_t)(k0 + i) * DD + e0;
    const float4 ba = *(const float4*)(b1r);
    const float4 bb = *(const float4*)(b1r + 4);
    float p = 0.f;
    p = fmaf(fmaxf(acc[i][0] + ba.x, 0.f), wa.x, p);
    p = fmaf(fmaxf(acc[i][1] + ba.y, 0.f), wa.y, p);
    p = fmaf(fmaxf(acc[i][2] + ba.z, 0.f), wa.z, p);
    p = fmaf(fmaxf(acc[i][3] + ba.w, 0.f), wa.w, p);
    p = fmaf(fmaxf(acc[i][4] + bb.x, 0.f), wb.x, p);
    p = fmaf(fmaxf(acc[i][5] + bb.y, 0.f), wb.y, p);
    p = fmaf(fmaxf(acc[i][6] + bb.z, 0.f), wb.z, p);
    p = fmaf(fmaxf(acc[i][7] + bb.w, 0.f), wb.w, p);
    // reduce across the 32 ec-lanes (masks <=16 stay within the kr half)
#pragma unroll
    for (int m = 16; m > 0; m >>= 1) p += __shfl_xor(p, m, 64);
    lg[i] = p;
  }
  if (ec == 0) {
#pragma unroll
    for (int i = 0; i < 8; ++i)
      s_logits[k0 + i] = lg[i] + s_b2p[k0 + i][0] + s_b2p[k0 + i][1] +
                         s_b2p[k0 + i][2] + s_b2p[k0 + i][3];
  }
  __syncthreads();

  // ---- softmax over K=64 (wave 0) ----
  if (wv == 0) {
    const int lane = tid & 63;
    const float v = s_logits[lane];
    float mx = v;
#pragma unroll
    for (int m = 32; m > 0; m >>= 1) mx = fmaxf(mx, __shfl_xor(mx, m, 64));
    const float e = expf(v - mx);
    float ssum = e;
#pragma unroll
    for (int m = 32; m > 0; m >>= 1) ssum += __shfl_xor(ssum, m, 64);
    s_score[lane] = e / ssum;
  }
  __syncthreads();

  // ---- weighted aggregation (scores near one-hot; skip is wave-uniform) ----
  float wsum = 0.f;
  for (int k = 0; k < KK; ++k) {
    const float sc = s_score[k];
    if (sc > 1e-12f) wsum = fmaf(sc, ent_table[(size_t)s_tail[k] * DD + tid], wsum);
  }
  s_de[tid] = wsum;
  s_de[DD + tid] = s_drug[tid];
  __syncthreads();

  // ---- x = relu([weighted, drug] @ lin_w + lin_b) ----
  float xj = lin_b[tid];
#pragma unroll 8
  for (int i = 0; i < 2 * DD; ++i) xj = fmaf(s_de[i], lin_w[(size_t)i * DD + tid], xj);
  x_out[(size_t)n * DD + tid] = fmaxf(xj, 0.f);
}

extern "C" __global__ __launch_bounds__(256) void bn_kernel(
    const float* __restrict__ x,
    const float* __restrict__ bn_w,
    const float* __restrict__ bn_b,
    float* __restrict__ out) {
  __shared__ float s_s[4], s_s2[4];
  const int d = blockIdx.x;   // one column per block
  const int tid = threadIdx.x;
  const int lane = tid & 63, wv = tid >> 6;
  float v[4];
  float s = 0.f, s2 = 0.f;
#pragma unroll
  for (int u = 0; u < 4; ++u) {
    const int r = tid + u * 256;
    v[u] = (r < NN) ? x[(size_t)r * DD + d] : 0.f;
    s += v[u];
    s2 = fmaf(v[u], v[u], s2);
  }
  s = wave_reduce_sum(s);
  s2 = wave_reduce_sum(s2);
  if (lane == 0) { s_s[wv] = s; s_s2[wv] = s2; }
  __syncthreads();
  const float S = s_s[0] + s_s[1] + s_s[2] + s_s[3];
  const float S2 = s_s2[0] + s_s2[1] + s_s2[2] + s_s2[3];
  const float mean = S / (float)NN;
  const float var = S2 / (float)NN - mean * mean;   // biased, matches jnp.var
  const float scale = (1.0f / sqrtf(var + BN_EPS)) * bn_w[d];
  const float shift = bn_b[d];
#pragma unroll
  for (int u = 0; u < 4; ++u) {
    const int r = tid + u * 256;
    if (r < NN) out[(size_t)r * DD + d] = (v[u] - mean) * scale + shift;
  }
}

extern "C" void kernel_launch(void* const* d_in, const int* in_sizes, int n_in,
                              void* d_out, int out_size, void* d_ws, size_t ws_size,
                              hipStream_t stream) {
  const int* drug_name = (const int*)d_in[0];
  const int* adj_tail = (const int*)d_in[1];
  const int* adj_rel = (const int*)d_in[2];
  const float* drug_table = (const float*)d_in[3];
  const float* rela_table = (const float*)d_in[4];
  const float* ent_table = (const float*)d_in[5];
  const float* W1 = (const float*)d_in[6];
  const float* b1 = (const float*)d_in[7];
  const float* W2 = (const float*)d_in[8];
  const float* b2 = (const float*)d_in[9];
  const float* lin_w = (const float*)d_in[10];
  const float* lin_b = (const float*)d_in[11];
  const float* bn_w = (const float*)d_in[12];
  const float* bn_b = (const float*)d_in[13];

  float* x = (float*)d_ws;  // [NN][DD] intermediate (pre-BN)

  fused_gnn<<<NN, 256, 0, stream>>>(drug_name, adj_tail, adj_rel, drug_table,
                                    rela_table, ent_table, W1, b1, W2, b2,
                                    lin_w, lin_b, x);
  bn_kernel<<<DD, 256, 0, stream>>>(x, bn_w, bn_b, (float*)d_out);
}

// Round 3
// 636.531 us; speedup vs baseline: 1.0229x; 1.0229x over previous
//
#include <hip/hip_runtime.h>
#include <math.h>

#define NN 846
#define KK 64
#define DD 256
constexpr float BN_EPS = 1e-5f;

__device__ __forceinline__ float wave_reduce_sum(float v) {
#pragma unroll
  for (int m = 32; m > 0; m >>= 1) v += __shfl_xor(v, m, 64);
  return v;
}

extern "C" __global__ __launch_bounds__(256) void fused_gnn(
    const int* __restrict__ drug_name,
    const int* __restrict__ adj_tail,
    const int* __restrict__ adj_rel,
    const float* __restrict__ drug_table,
    const float* __restrict__ rela_table,
    const float* __restrict__ ent_table,
    const float* __restrict__ W1,
    const float* __restrict__ b1,
    const float* __restrict__ W2,
    const float* __restrict__ b2,
    const float* __restrict__ lin_w,
    const float* __restrict__ lin_b,
    float* __restrict__ x_out) {
  // DR chunk, TRANSPOSED: [dd][k]. Row stride 68 floats = 272 B (16B-aligned,
  // bank phase +4 per row -> scalar column writes are 2-way = free; GEMM reads
  // are same-address broadcasts).
  __shared__ float s_dr_t[64][68];
  __shared__ float s_w2s[256];      // row-sums of W2[n]
  __shared__ float s_b2p[64][5];    // b2 row-sum partials (4 segs + pad)
  __shared__ float s_drug[256];
  __shared__ float s_de[512];       // concat(weighted, drug)
  __shared__ float s_score[64];
  __shared__ float s_logits[64];
  __shared__ int s_rel[64];
  __shared__ int s_tail[64];

  const int n = blockIdx.x;
  const int tid = threadIdx.x;
  const int wv = tid >> 6;   // wave 0..3
  const int kr = tid >> 5;   // 0..7  (k-tile row)
  const int ec = tid & 31;   // 0..31 (e-tile col)
  const int e0 = ec * 8;
  const int k0 = kr * 8;

  if (tid < 64) {
    s_rel[tid] = adj_rel[n * KK + tid];
    s_tail[tid] = adj_tail[n * KK + tid];
  }
  const int dn = drug_name[n];
  s_drug[tid] = drug_table[(size_t)dn * DD + tid];

  // ---- b2 row-sum partials: 4 threads per row, 64B segments (L2-resident) ----
  {
    const int row = tid >> 2, seg = tid & 3;
    const float4* p = (const float4*)(b2 + (size_t)row * DD + seg * 64);
    float4 s4 = make_float4(0.f, 0.f, 0.f, 0.f);
#pragma unroll
    for (int j = 0; j < 16; ++j) {
      const float4 v = p[j];
      s4.x += v.x; s4.y += v.y; s4.z += v.z; s4.w += v.w;
    }
    s_b2p[row][seg] = s4.x + s4.y + s4.z + s4.w;
  }

  const float* W1n = W1 + (size_t)n * DD * DD;
  const float* W2n = W2 + (size_t)n * DD * DD;

  float acc[8][8];
#pragma unroll
  for (int i = 0; i < 8; ++i)
#pragma unroll
    for (int j = 0; j < 8; ++j) acc[i][j] = 0.f;

  float w2acc = 0.f;  // thread owns W2 row `tid`, accumulated across chunks

  for (int c = 0; c < 4; ++c) {
    const int d0 = c * 64;
    __syncthreads();  // prev-chunk readers of s_dr_t done (also initial visibility)

    // ---- build DR_T chunk: s_dr_t[dd][k] = drug[d0+dd] * rela[rel[k]][d0+dd] ----
    {
      const int kq = tid & 63;
      const int dq = wv * 16;
      const float* rr = rela_table + (size_t)s_rel[kq] * DD + d0 + dq;
      const float4 r0 = *(const float4*)(rr + 0);
      const float4 r1 = *(const float4*)(rr + 4);
      const float4 r2 = *(const float4*)(rr + 8);
      const float4 r3 = *(const float4*)(rr + 12);
      const float rv[16] = {r0.x, r0.y, r0.z, r0.w, r1.x, r1.y, r1.z, r1.w,
                            r2.x, r2.y, r2.z, r2.w, r3.x, r3.y, r3.z, r3.w};
#pragma unroll
      for (int u = 0; u < 16; ++u)
        s_dr_t[dq + u][kq] = s_drug[d0 + dq + u] * rv[u];
    }

    // ---- W2 row-sum slice for this chunk: own row, 16 float4, pure ILP ----
    {
      const float4* p = (const float4*)(W2n + (size_t)tid * DD + d0);
      float4 s4 = make_float4(0.f, 0.f, 0.f, 0.f);
#pragma unroll
      for (int j = 0; j < 16; ++j) {
        const float4 v = p[j];
        s4.x += v.x; s4.y += v.y; s4.z += v.z; s4.w += v.w;
      }
      w2acc += s4.x + s4.y + s4.z + s4.w;
    }

    __syncthreads();  // DR_T ready

    // ---- barrier-free GEMM over this chunk: W1 direct global->reg,
    //      1-row software prefetch so loads issue before the FMA burst ----
    const float* wbase = W1n + (size_t)d0 * DD + e0;
    float4 w0 = *(const float4*)(wbase);
    float4 w1v = *(const float4*)(wbase + 4);
#pragma unroll 2
    for (int dd = 0; dd < 64; ++dd) {
      const int ndd = (dd < 63) ? dd + 1 : 63;
      const float* nxt = wbase + (size_t)ndd * DD;
      const float4 nw0 = *(const float4*)(nxt);
      const float4 nw1 = *(const float4*)(nxt + 4);
      const float4 a0 = *(const float4*)&s_dr_t[dd][k0];
      const float4 a1 = *(const float4*)&s_dr_t[dd][k0 + 4];
      const float av[8] = {a0.x, a0.y, a0.z, a0.w, a1.x, a1.y, a1.z, a1.w};
#pragma unroll
      for (int i = 0; i < 8; ++i) {
        acc[i][0] = fmaf(av[i], w0.x, acc[i][0]);
        acc[i][1] = fmaf(av[i], w0.y, acc[i][1]);
        acc[i][2] = fmaf(av[i], w0.z, acc[i][2]);
        acc[i][3] = fmaf(av[i], w0.w, acc[i][3]);
        acc[i][4] = fmaf(av[i], w1v.x, acc[i][4]);
        acc[i][5] = fmaf(av[i], w1v.y, acc[i][5]);
        acc[i][6] = fmaf(av[i], w1v.z, acc[i][6]);
        acc[i][7] = fmaf(av[i], w1v.w, acc[i][7]);
      }
      w0 = nw0;
      w1v = nw1;
    }
  }

  s_w2s[tid] = w2acc;
  __syncthreads();

  // ---- epilogue: h1 = relu(acc + b1); logit[k] = dot(h1[k,:], W2s) + b2s[k] ----
  const float4 wa = *(const float4*)&s_w2s[e0];
  const float4 wb = *(const float4*)&s_w2s[e0 + 4];
  float lg[8];
#pragma unroll
  for (int i = 0; i < 8; ++i) {
    const float* b1r = b1 + (size_t)(k0 + i) * DD + e0;
    const float4 ba = *(const float4*)(b1r);
    const float4 bb = *(const float4*)(b1r + 4);
    float p = 0.f;
    p = fmaf(fmaxf(acc[i][0] + ba.x, 0.f), wa.x, p);
    p = fmaf(fmaxf(acc[i][1] + ba.y, 0.f), wa.y, p);
    p = fmaf(fmaxf(acc[i][2] + ba.z, 0.f), wa.z, p);
    p = fmaf(fmaxf(acc[i][3] + ba.w, 0.f), wa.w, p);
    p = fmaf(fmaxf(acc[i][4] + bb.x, 0.f), wb.x, p);
    p = fmaf(fmaxf(acc[i][5] + bb.y, 0.f), wb.y, p);
    p = fmaf(fmaxf(acc[i][6] + bb.z, 0.f), wb.z, p);
    p = fmaf(fmaxf(acc[i][7] + bb.w, 0.f), wb.w, p);
    // reduce across the 32 ec-lanes (masks <=16 stay within the kr half)
#pragma unroll
    for (int m = 16; m > 0; m >>= 1) p += __shfl_xor(p, m, 64);
    lg[i] = p;
  }
  if (ec == 0) {
#pragma unroll
    for (int i = 0; i < 8; ++i)
      s_logits[k0 + i] = lg[i] + s_b2p[k0 + i][0] + s_b2p[k0 + i][1] +
                         s_b2p[k0 + i][2] + s_b2p[k0 + i][3];
  }
  __syncthreads();

  // ---- softmax over K=64 (wave 0) ----
  if (wv == 0) {
    const int lane = tid & 63;
    const float v = s_logits[lane];
    float mx = v;
#pragma unroll
    for (int m = 32; m > 0; m >>= 1) mx = fmaxf(mx, __shfl_xor(mx, m, 64));
    const float e = expf(v - mx);
    float ssum = e;
#pragma unroll
    for (int m = 32; m > 0; m >>= 1) ssum += __shfl_xor(ssum, m, 64);
    s_score[lane] = e / ssum;
  }
  __syncthreads();

  // ---- weighted aggregation (scores near one-hot; skip is wave-uniform) ----
  float wsum = 0.f;
  for (int k = 0; k < KK; ++k) {
    const float sc = s_score[k];
    if (sc > 1e-12f) wsum = fmaf(sc, ent_table[(size_t)s_tail[k] * DD + tid], wsum);
  }
  s_de[tid] = wsum;
  s_de[DD + tid] = s_drug[tid];
  __syncthreads();

  // ---- x = relu([weighted, drug] @ lin_w + lin_b) ----
  float xj = lin_b[tid];
#pragma unroll 8
  for (int i = 0; i < 2 * DD; ++i) xj = fmaf(s_de[i], lin_w[(size_t)i * DD + tid], xj);
  x_out[(size_t)n * DD + tid] = fmaxf(xj, 0.f);
}

extern "C" __global__ __launch_bounds__(256) void bn_kernel(
    const float* __restrict__ x,
    const float* __restrict__ bn_w,
    const float* __restrict__ bn_b,
    float* __restrict__ out) {
  __shared__ float s_s[4], s_s2[4];
  const int d = blockIdx.x;   // one column per block
  const int tid = threadIdx.x;
  const int lane = tid & 63, wv = tid >> 6;
  float v[4];
  float s = 0.f, s2 = 0.f;
#pragma unroll
  for (int u = 0; u < 4; ++u) {
    const int r = tid + u * 256;
    v[u] = (r < NN) ? x[(size_t)r * DD + d] : 0.f;
    s += v[u];
    s2 = fmaf(v[u], v[u], s2);
  }
  s = wave_reduce_sum(s);
  s2 = wave_reduce_sum(s2);
  if (lane == 0) { s_s[wv] = s; s_s2[wv] = s2; }
  __syncthreads();
  const float S = s_s[0] + s_s[1] + s_s[2] + s_s[3];
  const float S2 = s_s2[0] + s_s2[1] + s_s2[2] + s_s2[3];
  const float mean = S / (float)NN;
  const float var = S2 / (float)NN - mean * mean;   // biased, matches jnp.var
  const float scale = (1.0f / sqrtf(var + BN_EPS)) * bn_w[d];
  const float shift = bn_b[d];
#pragma unroll
  for (int u = 0; u < 4; ++u) {
    const int r = tid + u * 256;
    if (r < NN) out[(size_t)r * DD + d] = (v[u] - mean) * scale + shift;
  }
}

extern "C" void kernel_launch(void* const* d_in, const int* in_sizes, int n_in,
                              void* d_out, int out_size, void* d_ws, size_t ws_size,
                              hipStream_t stream) {
  const int* drug_name = (const int*)d_in[0];
  const int* adj_tail = (const int*)d_in[1];
  const int* adj_rel = (const int*)d_in[2];
  const float* drug_table = (const float*)d_in[3];
  const float* rela_table = (const float*)d_in[4];
  const float* ent_table = (const float*)d_in[5];
  const float* W1 = (const float*)d_in[6];
  const float* b1 = (const float*)d_in[7];
  const float* W2 = (const float*)d_in[8];
  const float* b2 = (const float*)d_in[9];
  const float* lin_w = (const float*)d_in[10];
  const float* lin_b = (const float*)d_in[11];
  const float* bn_w = (const float*)d_in[12];
  const float* bn_b = (const float*)d_in[13];

  float* x = (float*)d_ws;  // [NN][DD] intermediate (pre-BN)

  fused_gnn<<<NN, 256, 0, stream>>>(drug_name, adj_tail, adj_rel, drug_table,
                                    rela_table, ent_table, W1, b1, W2, b2,
                                    lin_w, lin_b, x);
  bn_kernel<<<DD, 256, 0, stream>>>(x, bn_w, bn_b, (float*)d_out);
}